// Round 5
// baseline (424.109 us; speedup 1.0000x reference)
//
#include <hip/hip_runtime.h>

// 4-level Haar DWT + IDWT round-trip, (32*512*4096) fp32.
// One thread owns 4 contiguous floats per tile (one dwordx4, fully
// coalesced); 2 wave-strided tiles per thread for MLP + index amortization.
// Levels 1-2 lane-local; levels 3-4 butterfly across lanes via __shfl_xor
// (both lanes compute the duplicated coarse/detail), synthesis lane-local.
// Same fp32 op sequence as the JAX reference. No nt hints (R4 showed -2%).

typedef float f32x4 __attribute__((ext_vector_type(4)));

__device__ __forceinline__ f32x4 haar_rt4(f32x4 r, int lane) {
  const float S = 0.7071067811865476f;  // fp32(1/sqrt(2))
  // ---- Analysis ----
  float a1_0 = (r.x + r.y) * S, d1_0 = (r.x - r.y) * S;
  float a1_1 = (r.z + r.w) * S, d1_1 = (r.z - r.w) * S;
  float a2 = (a1_0 + a1_1) * S, d2 = (a1_0 - a1_1) * S;
  // L3: pair lanes (2j, 2j+1)
  float p1 = __shfl_xor(a2, 1);
  float e3 = (lane & 1) ? p1 : a2;
  float o3 = (lane & 1) ? a2 : p1;
  float a3 = (e3 + o3) * S, d3 = (e3 - o3) * S;
  // L4: pair lane-pairs
  float p2 = __shfl_xor(a3, 2);
  float e4 = (lane & 2) ? p2 : a3;
  float o4 = (lane & 2) ? a3 : p2;
  float a4 = (e4 + o4) * S, d4 = (e4 - o4) * S;
  // ---- Synthesis (lane-local) ----
  float b3 = (lane & 2) ? (a4 - d4) * S : (a4 + d4) * S;
  float b2 = (lane & 1) ? (b3 - d3) * S : (b3 + d3) * S;
  float b1_0 = (b2 + d2) * S;
  float b1_1 = (b2 - d2) * S;
  f32x4 o4v;
  o4v.x = (b1_0 + d1_0) * S;
  o4v.y = (b1_0 - d1_0) * S;
  o4v.z = (b1_1 + d1_1) * S;
  o4v.w = (b1_1 - d1_1) * S;
  return o4v;
}

__global__ __launch_bounds__(256) void wavelet_rt_kernel(
    const f32x4* __restrict__ in, f32x4* __restrict__ out) {
  const int lane = threadIdx.x & 63;
  // Block owns 512 consecutive float4s: two 256-wide slabs.
  int t0 = blockIdx.x * 512 + threadIdx.x;
  int t1 = t0 + 256;

  f32x4 r0 = in[t0];
  f32x4 r1 = in[t1];
  f32x4 o0 = haar_rt4(r0, lane);
  f32x4 o1 = haar_rt4(r1, lane);
  out[t0] = o0;
  out[t1] = o1;
}

extern "C" void kernel_launch(void* const* d_in, const int* in_sizes, int n_in,
                              void* d_out, int out_size, void* d_ws, size_t ws_size,
                              hipStream_t stream) {
  const float* x = (const float*)d_in[0];
  float* out = (float*)d_out;
  int n4 = out_size / 4;          // 16,777,216 float4s
  int grid = n4 / 512;            // 32,768 blocks, exact (out_size = 2^26)
  wavelet_rt_kernel<<<grid, 256, 0, stream>>>(
      (const f32x4*)x, (f32x4*)out);
}